// Round 6
// baseline (337.090 us; speedup 1.0000x reference)
//
#include <hip/hip_runtime.h>
#include <stdint.h>
#include <stddef.h>

typedef int v4i  __attribute__((ext_vector_type(4)));
typedef int v16i __attribute__((ext_vector_type(16)));
typedef _Float16 vh8 __attribute__((ext_vector_type(8)));

#define GELU_A   (-0.2888f)
#define GELU_B   (-1.769f)
#define INV_SQRT2 0.70710678118654752440f

// async 16B global->LDS (lane i's 16B lands at ldsbase + i*16; ldsbase wave-uniform)
#define GLD16(gp, lp) __builtin_amdgcn_global_load_lds( \
    (const __attribute__((address_space(1))) unsigned int*)(gp), \
    (__attribute__((address_space(3))) unsigned int*)(lp), 16, 0, 0)

// gfx9 s_waitcnt imm: vmcnt[3:0]=bits3:0, expcnt=bits6:4, lgkmcnt=bits11:8, vmcnt[5:4]=bits15:14
#define WAIT_VM0   0x0F70   // vmcnt(0),  lgkm free
#define WAIT_LGKM0 0xC07F   // lgkmcnt(0), vmcnt free (=63)

// scalar slots: sc[0]=enc(xmin) sc[1]=enc(gmin)  [init 0xFFFFFFFF]
//               sc[2]=enc(xmax) sc[3]=|w1|max bits sc[4]=|w2|max bits sc[5]=enc(gmax) [init 0]

__device__ __forceinline__ unsigned enc_f(float f){
  unsigned u = __float_as_uint(f);
  return (u & 0x80000000u) ? ~u : (u | 0x80000000u);
}
__device__ __forceinline__ float dec_f(unsigned e){
  unsigned u = (e & 0x80000000u) ? (e & 0x7FFFFFFFu) : ~e;
  return __uint_as_float(u);
}

__device__ __forceinline__ float int_gelu_f(float x){
  float t = x * INV_SQRT2;
  float at = fminf(fabsf(t), 1.769f);
  float u = at + GELU_B;                 // in [-1.769, 0]
  float p = GELU_A * (u * u) + 1.0f;
  float L = (t > 0.0f) ? p : ((t < 0.0f) ? -p : 0.0f);
  return x * 0.5f * (1.0f + L);
}

// blocks [0,1024): x min/max; [1024,1152): absmax w1 -> sc[3]; [1152,1280): absmax w2 -> sc[4]
__global__ __launch_bounds__(256) void reduce_stats(
    const float4* __restrict__ x, int nx4,
    const float4* __restrict__ w1, int n14,
    const float4* __restrict__ w2, int n24,
    unsigned* __restrict__ sc)
{
  __shared__ float ra[256], rb[256];
  const int tid = threadIdx.x;
  const int b = blockIdx.x;
  if (b < 1024){
    float lmin = 3.4e38f, lmax = -3.4e38f;
    for (long i = (long)b * 256 + tid; i < nx4; i += 1024L * 256L){
      float4 v = x[i];
      lmin = fminf(lmin, fminf(fminf(v.x, v.y), fminf(v.z, v.w)));
      lmax = fmaxf(lmax, fmaxf(fmaxf(v.x, v.y), fmaxf(v.z, v.w)));
    }
    ra[tid] = lmin; rb[tid] = lmax;
    __syncthreads();
    for (int s = 128; s > 0; s >>= 1){
      if (tid < s){ ra[tid] = fminf(ra[tid], ra[tid + s]); rb[tid] = fmaxf(rb[tid], rb[tid + s]); }
      __syncthreads();
    }
    if (tid == 0){
      atomicMin(&sc[0], enc_f(ra[0]));
      atomicMax(&sc[2], enc_f(rb[0]));
    }
  } else {
    const float4* w; int n4; int slot; int bl;
    if (b < 1152){ w = w1; n4 = n14; slot = 3; bl = b - 1024; }
    else         { w = w2; n4 = n24; slot = 4; bl = b - 1152; }
    float la = 0.0f;
    for (long i = (long)bl * 256 + tid; i < n4; i += 128L * 256L){
      float4 v = w[i];
      la = fmaxf(la, fmaxf(fmaxf(fabsf(v.x), fabsf(v.y)), fmaxf(fabsf(v.z), fabsf(v.w))));
    }
    ra[tid] = la;
    __syncthreads();
    for (int s = 128; s > 0; s >>= 1){
      if (tid < s) ra[tid] = fmaxf(ra[tid], ra[tid + s]);
      __syncthreads();
    }
    if (tid == 0) atomicMax(&sc[slot], __float_as_uint(ra[0]));
  }
}

// fused: blocks [0,2048) act-quant x -> qx ((q-128) int8, packed u32, LINEAR);
//        blocks [2048, 2048+H+D) weight-quant rows (+row sums), LINEAR
__global__ __launch_bounds__(256) void quant_all(
    const float4* __restrict__ x, unsigned* __restrict__ qx, long nx4,
    const float* __restrict__ w1, const float* __restrict__ w2,
    int8_t* __restrict__ qw1, int8_t* __restrict__ qw2,
    int* __restrict__ rs1, int* __restrict__ rs2,
    const unsigned* __restrict__ sc, int H, int D)
{
  const int tid = threadIdx.x;
  const int b = blockIdx.x;
  if (b < 2048){
    const float vmin = dec_f(sc[0]);
    const float vmax = dec_f(sc[2]);
    const float s  = fmaxf(vmax - vmin, 1e-8f) / 255.0f;
    const float zp = rintf(-vmin / s);
    for (long i = (long)b * 256 + tid; i < nx4; i += 2048L * 256L){
      float4 v = x[i];
      int q0 = (int)fminf(fmaxf(rintf(v.x / s) + zp, 0.0f), 255.0f) - 128;
      int q1 = (int)fminf(fmaxf(rintf(v.y / s) + zp, 0.0f), 255.0f) - 128;
      int q2 = (int)fminf(fmaxf(rintf(v.z / s) + zp, 0.0f), 255.0f) - 128;
      int q3 = (int)fminf(fmaxf(rintf(v.w / s) + zp, 0.0f), 255.0f) - 128;
      qx[i] = ((unsigned)(q0 & 255)) | ((unsigned)(q1 & 255) << 8) |
              ((unsigned)(q2 & 255) << 16) | ((unsigned)(q3 & 255) << 24);
    }
  } else {
    __shared__ int red[256];
    const int wb = b - 2048;
    const float* w; int8_t* q; int* rs; int K; int n; float s;
    if (wb < H){ w = w1; q = qw1; rs = rs1; K = D; n = wb;
                 s = fmaxf(__uint_as_float(sc[3]), 1e-8f) / 127.0f; }
    else       { w = w2; q = qw2; rs = rs2; K = H; n = wb - H;
                 s = fmaxf(__uint_as_float(sc[4]), 1e-8f) / 127.0f; }
    int sum = 0;
    for (int k = tid; k < K; k += 256){
      float v = w[(size_t)n * K + k];
      float qf = fminf(fmaxf(rintf(v / s), -128.0f), 127.0f);
      int qi = (int)qf;
      q[(size_t)n * K + k] = (int8_t)qi;
      sum += qi;
    }
    red[tid] = sum;
    __syncthreads();
    for (int st = 128; st > 0; st >>= 1){
      if (tid < st) red[tid] += red[tid + st];
      __syncthreads();
    }
    if (tid == 0) rs[n] = red[0];
  }
}

// elementwise: fp16 g (LINEAR) -> int8 qg ((q-128), LINEAR), using g stats
__global__ __launch_bounds__(256) void quant_g(
    const vh8* __restrict__ g, uint2* __restrict__ qg, long n8,
    const unsigned* __restrict__ sc)
{
  const float gmin = dec_f(sc[1]), gmax = dec_f(sc[5]);
  const float qs  = fmaxf(gmax - gmin, 1e-8f) / 255.0f;
  const float qzp = rintf(-gmin / qs);
  const long stride = (long)gridDim.x * blockDim.x;
  for (long i = (long)blockIdx.x * blockDim.x + threadIdx.x; i < n8; i += stride){
    vh8 v = g[i];
    unsigned lo = 0, hi = 0;
#pragma unroll
    for (int j = 0; j < 4; j++){
      int q = (int)fminf(fmaxf(rintf((float)v[j] / qs) + qzp, 0.0f), 255.0f) - 128;
      lo |= ((unsigned)(q & 255)) << (8 * j);
    }
#pragma unroll
    for (int j = 0; j < 4; j++){
      int q = (int)fminf(fmaxf(rintf((float)v[4 + j] / qs) + qzp, 0.0f), 255.0f) - 128;
      hi |= ((unsigned)(q & 255)) << (8 * j);
    }
    uint2 o; o.x = lo; o.y = hi;
    qg[i] = o;
  }
}

// MODE 0: h->gelu-> g min/max atomics only (no store)          [fallback pass A]
// MODE 3: h->gelu-> store g fp16 + g min/max atomics            [main pass A]
// MODE 2: h->gelu-> quantize with g stats -> store int8 (q-128) [fallback pass B]
// MODE 1: h + bias -> store fp32 out                            [GEMM2]
//
// 8-phase-template (T2+T3+T4+T5) adapted to i8: BM=BN=256, BK=128,
// mfma_i32_32x32x32_i8, 8 waves (512 thr) = 2M x 4N, wave tile 128x64
// (acc 4x2 of 32x32 = 128 AGPR). 2 LDS buffers of 64KB (A 32K + B 32K) = 128KB
// -> 1 block/CU (the template's regime; proven 62% MfmaUtil on bf16).
// Per K-tile (t, buf=t&1): 4 phases (kb=0..3), each:
//   { 6x ds_read_b128 (4 A-frags + 2 B-frags, XOR-chunk swizzled, conflict-free)
//     ; [kb==0: issue ALL 8 stage gld_lds for tile t+1 into buf^1]
//     ; sched_barrier ; [kb==3: vmcnt(0) -- drains loads issued ~3 phases ago]
//     ; s_barrier ; lgkmcnt(0) ; sched_barrier
//     ; setprio(1) 8x MFMA setprio(0) ; sched_barrier ; s_barrier }
// Race ledger: staging into buf^1 at tile-t kb0 is after tile t-1's last phase
// (lgkmcnt(0)-drained ds_reads + barrier) -> no read-write race. vmcnt(0) at
// kb3 validates tile t+1 before its first ds_read (tile t+1 kb0).
template<int MODE>
__global__ __launch_bounds__(512, 2) void gemm_i8p(
    const int8_t* __restrict__ A, const int8_t* __restrict__ Bm,
    const int* __restrict__ rowsum, const float* __restrict__ bias,
    void* __restrict__ Cout, int M, int N, int K,
    unsigned* __restrict__ sc)
{
  __shared__ __align__(16) int8_t lds[2][65536];   // per buf: A @0 (32K), B @32768 (32K)

  const int tid  = threadIdx.x;
  const int lane = tid & 63;
  const int wave = tid >> 6;           // 0..7
  const int l31  = lane & 31;
  const int kh   = lane >> 5;          // which 16B half of a 32-k block
  const int n0   = blockIdx.x * 256;
  const int m0   = blockIdx.y * 256;
  const int wm   = (wave >> 2) * 128;  // 0 / 128
  const int wn   = (wave & 3) * 64;    // 0 / 64 / 128 / 192
  const int NT   = K >> 7;             // 128-wide K tiles (6 or 24)

  // staging: per operand 4 gld_lds per wave per tile. instr i: half h=i>>1,
  // quarter q=i&1. Wave covers rows r0 = wave*16 + q*8 .. +8 of half h.
  // Lane L -> row r = r0 + (L>>3), phys chunk c = L&7,
  // src chunk cs = c ^ ((r>>1)&7)   (involution; read side applies same XOR).
  int aoff[4], boff[4], ldsoA[4], ldsoB[4];
#pragma unroll
  for (int i = 0; i < 4; i++){
    const int h = i >> 1, q = i & 1;
    const int r0 = wave * 16 + q * 8;
    const int r  = r0 + (lane >> 3);
    const int cs = (lane & 7) ^ ((r >> 1) & 7);
    int ga = m0 + h * 128 + r; if (ga >= M) ga = M - 1;  // clamp (dup rows, epilogue-guarded)
    aoff[i] = ga * K + cs * 16;
    boff[i] = (n0 + h * 128 + r) * K + cs * 16;          // N multiple of 256
    ldsoA[i] = h * 16384 + r0 * 128;
    ldsoB[i] = 32768 + h * 16384 + r0 * 128;
  }

  // fragment read constants. A frag (mi,kb): lane reads row wm+mi*32+l31,
  // logical chunk ch = kb*2+kh, phys = ch ^ ((r&127)>>1 & 7).
  // Bank check: 32 lanes/kh hit each of 8 phys values exactly 4x -> conflict-free.
  int raddrA[4], rswzA[4], raddrB[2], rswzB[2];
#pragma unroll
  for (int mi = 0; mi < 4; mi++){
    const int row = wm + mi * 32 + l31;
    raddrA[mi] = (row >> 7) * 16384 + (row & 127) * 128;
    rswzA[mi]  = ((row & 127) >> 1) & 7;
  }
#pragma unroll
  for (int nj = 0; nj < 2; nj++){
    const int row = wn + nj * 32 + l31;
    raddrB[nj] = 32768 + (row >> 7) * 16384 + (row & 127) * 128;
    rswzB[nj]  = ((row & 127) >> 1) & 7;
  }

  v16i acc[4][2] = {};

  // prologue: stage tile 0 into buf 0, drain, sync
#pragma unroll
  for (int i = 0; i < 4; i++) GLD16(A  + aoff[i], &lds[0][ldsoA[i]]);
#pragma unroll
  for (int i = 0; i < 4; i++) GLD16(Bm + boff[i], &lds[0][ldsoB[i]]);
  __builtin_amdgcn_s_waitcnt(WAIT_VM0);
  __builtin_amdgcn_s_barrier();

  for (int t = 0; t < NT; t++){
    const int8_t* buf = &lds[t & 1][0];
    int8_t* nbuf = &lds[(t + 1) & 1][0];
    const bool pf = (t + 1 < NT);
    const int ko = (t + 1) << 7;

#pragma unroll
    for (int kb = 0; kb < 4; kb++){
      v4i af[4], bf[2];
      const int ch = kb * 2 + kh;
#pragma unroll
      for (int mi = 0; mi < 4; mi++)
        af[mi] = *(const v4i*)(buf + raddrA[mi] + ((ch ^ rswzA[mi]) << 4));
#pragma unroll
      for (int nj = 0; nj < 2; nj++)
        bf[nj] = *(const v4i*)(buf + raddrB[nj] + ((ch ^ rswzB[nj]) << 4));

      if (kb == 0 && pf){
#pragma unroll
        for (int i = 0; i < 4; i++) GLD16(A  + aoff[i] + ko, nbuf + ldsoA[i]);
#pragma unroll
        for (int i = 0; i < 4; i++) GLD16(Bm + boff[i] + ko, nbuf + ldsoB[i]);
      }
      __builtin_amdgcn_sched_barrier(0);
      if (kb == 3) __builtin_amdgcn_s_waitcnt(WAIT_VM0);  // tile t+1 staged (issued at kb0)
      __builtin_amdgcn_s_barrier();
      __builtin_amdgcn_s_waitcnt(WAIT_LGKM0);
      __builtin_amdgcn_sched_barrier(0);
      __builtin_amdgcn_s_setprio(1);
#pragma unroll
      for (int mi = 0; mi < 4; mi++)
#pragma unroll
        for (int nj = 0; nj < 2; nj++)
          acc[mi][nj] = __builtin_amdgcn_mfma_i32_32x32x32_i8(af[mi], bf[nj], acc[mi][nj], 0, 0, 0);
      __builtin_amdgcn_s_setprio(0);
      __builtin_amdgcn_sched_barrier(0);
      __builtin_amdgcn_s_barrier();
    }
  }

  // epilogue scalars
  float s_h, off_h;
  if constexpr (MODE == 1){
    float gmin = dec_f(sc[1]), gmax = dec_f(sc[5]);
    float sg = fmaxf(gmax - gmin, 1e-8f) / 255.0f;
    float zp = rintf(-gmin / sg);
    float sw = fmaxf(__uint_as_float(sc[4]), 1e-8f) / 127.0f;
    s_h = sg * sw; off_h = 128.0f - zp;
  } else {
    float xmin = dec_f(sc[0]), xmax = dec_f(sc[2]);
    float sx = fmaxf(xmax - xmin, 1e-8f) / 255.0f;
    float zp = rintf(-xmin / sx);
    float sw = fmaxf(__uint_as_float(sc[3]), 1e-8f) / 127.0f;
    s_h = sx * sw; off_h = 128.0f - zp;
  }
  float qs = 1.0f, qzp = 0.0f;
  if constexpr (MODE == 2){
    float gmin = dec_f(sc[1]), gmax = dec_f(sc[5]);
    qs = fmaxf(gmax - gmin, 1e-8f) / 255.0f;
    qzp = rintf(-gmin / qs);
  }

  // C/D 32x32 layout: col = lane&31, row = (reg&3) + 8*(reg>>2) + 4*(lane>>5)
  float lmin = 3.4e38f, lmax = -3.4e38f;
#pragma unroll
  for (int nj = 0; nj < 2; nj++){
    const int n = n0 + wn + nj * 32 + l31;
    const float rsv = off_h * (float)rowsum[n];
    const float bv = bias[n];
#pragma unroll
    for (int mi = 0; mi < 4; mi++){
      const int mbase = m0 + wm + mi * 32 + 4 * kh;
#pragma unroll
      for (int r = 0; r < 16; r++){
        const int m = mbase + (r & 3) + 8 * (r >> 2);
        if (m < M){
          float h = s_h * ((float)acc[mi][nj][r] + rsv) + bv;
          if constexpr (MODE == 0){
            float gv = int_gelu_f(h);
            lmin = fminf(lmin, gv); lmax = fmaxf(lmax, gv);
          } else if constexpr (MODE == 3){
            float gv = int_gelu_f(h);
            lmin = fminf(lmin, gv); lmax = fmaxf(lmax, gv);
            ((_Float16*)Cout)[(size_t)m * N + n] = (_Float16)gv;
          } else if constexpr (MODE == 2){
            float gv = int_gelu_f(h);
            float qf = fminf(fmaxf(rintf(gv / qs) + qzp, 0.0f), 255.0f);
            ((int8_t*)Cout)[(size_t)m * N + n] = (int8_t)((int)qf - 128);
          } else {
            ((float*)Cout)[(size_t)m * N + n] = h;
          }
        }
      }
    }
  }

  if constexpr (MODE == 0 || MODE == 3){
    __syncthreads();                   // all waves done with LDS -> reuse as scratch
    float* redA = (float*)&lds[0][0];
    float* redB = ((float*)&lds[0][0]) + 512;
    redA[tid] = lmin; redB[tid] = lmax;
    __syncthreads();
    for (int st = 256; st > 0; st >>= 1){
      if (tid < st){
        redA[tid] = fminf(redA[tid], redA[tid + st]);
        redB[tid] = fmaxf(redB[tid], redB[tid + st]);
      }
      __syncthreads();
    }
    if (tid == 0){
      atomicMin(&sc[1], enc_f(redA[0]));
      atomicMax(&sc[5], enc_f(redB[0]));
    }
  }
}

extern "C" void kernel_launch(void* const* d_in, const int* in_sizes, int n_in,
                              void* d_out, int out_size, void* d_ws, size_t ws_size,
                              hipStream_t stream)
{
  const float* x  = (const float*)d_in[0];
  const float* w1 = (const float*)d_in[1];
  const float* b1 = (const float*)d_in[2];
  const float* w2 = (const float*)d_in[3];
  const float* b2 = (const float*)d_in[4];
  float* out = (float*)d_out;

  const int H = in_sizes[2];            // 3072
  const int D = in_sizes[4];            // 768
  const int M = in_sizes[0] / D;        // 12608

  char* ws = (char*)d_ws;
  unsigned* sc = (unsigned*)ws;
  size_t off = 256;
  int8_t* qx  = (int8_t*)(ws + off); off += (size_t)M * D;   // 9.68 MB
  int8_t* qw1 = (int8_t*)(ws + off); off += (size_t)H * D;   // 2.36 MB
  int8_t* qw2 = (int8_t*)(ws + off); off += (size_t)D * H;   // 2.36 MB
  int* rs1 = (int*)(ws + off); off += (size_t)H * 4;
  int* rs2 = (int*)(ws + off); off += 4096;
  int8_t* qg  = (int8_t*)(ws + off); off += (size_t)M * H;   // 38.7 MB
  _Float16* g16 = (_Float16*)(ws + off);                      // 77.5 MB (big path)
  const size_t need_big = off + (size_t)M * H * 2;
  (void)n_in; (void)out_size;

  // scalar init: slots 0,1 = 0xFFFFFFFF (encoded +inf for min); 2..5 = 0
  hipMemsetAsync(sc, 0xFF, 8, stream);
  hipMemsetAsync(sc + 2, 0x00, 16, stream);

  reduce_stats<<<dim3(1280), dim3(256), 0, stream>>>(
      (const float4*)x, M * D / 4,
      (const float4*)w1, H * D / 4,
      (const float4*)w2, D * H / 4, sc);

  quant_all<<<dim3(2048 + H + D), dim3(256), 0, stream>>>(
      (const float4*)x, (unsigned*)qx, (long)M * D / 4,
      w1, w2, qw1, qw2, rs1, rs2, sc, H, D);

  // GEMM1: 256x256 tile, grid (12, 50). GEMM2: 256x256 tile, grid (3, 50).
  const dim3 g1(H / 256, (M + 255) / 256), g2(D / 256, (M + 255) / 256), blk(512);

  if (ws_size >= need_big){
    // GEMM1 (single pass): g stats + store g fp16
    gemm_i8p<3><<<g1, blk, 0, stream>>>(qx, qw1, rs1, b1, g16, M, H, D, sc);
    // elementwise quantize g -> qg
    quant_g<<<dim3(2048), dim3(256), 0, stream>>>(
        (const vh8*)g16, (uint2*)qg, (long)M * H / 8, sc);
  } else {
    // fallback: exact 2-pass GEMM1 (stats, then quantize)
    gemm_i8p<0><<<g1, blk, 0, stream>>>(qx, qw1, rs1, b1, nullptr, M, H, D, sc);
    gemm_i8p<2><<<g1, blk, 0, stream>>>(qx, qw1, rs1, b1, qg, M, H, D, sc);
  }

  // GEMM2: out = qg @ qw2^T + b2
  gemm_i8p<1><<<g2, blk, 0, stream>>>(qg, qw2, rs2, b2, out, M, D, H, sc);
}

// Round 7
// 332.440 us; speedup vs baseline: 1.0140x; 1.0140x over previous
//
#include <hip/hip_runtime.h>
#include <stdint.h>
#include <stddef.h>

typedef int v4i  __attribute__((ext_vector_type(4)));
typedef int v16i __attribute__((ext_vector_type(16)));
typedef _Float16 vh8 __attribute__((ext_vector_type(8)));

#define GELU_A   (-0.2888f)
#define GELU_B   (-1.769f)
#define INV_SQRT2 0.70710678118654752440f

// async 16B global->LDS (lane i's 16B lands at ldsbase + i*16; ldsbase wave-uniform)
#define GLD16(gp, lp) __builtin_amdgcn_global_load_lds( \
    (const __attribute__((address_space(1))) unsigned int*)(gp), \
    (__attribute__((address_space(3))) unsigned int*)(lp), 16, 0, 0)

// gfx9 s_waitcnt imm: vmcnt[3:0]=bits3:0, expcnt=bits6:4, lgkmcnt=bits11:8
#define WAIT_VM2   0x0F72   // vmcnt(2)
#define WAIT_VM0   0x0F70   // vmcnt(0)

// scalar slots: sc[0]=enc(xmin) sc[1]=enc(gmin)  [init 0xFFFFFFFF]
//               sc[2]=enc(xmax) sc[3]=|w1|max bits sc[4]=|w2|max bits sc[5]=enc(gmax) [init 0]

__device__ __forceinline__ unsigned enc_f(float f){
  unsigned u = __float_as_uint(f);
  return (u & 0x80000000u) ? ~u : (u | 0x80000000u);
}
__device__ __forceinline__ float dec_f(unsigned e){
  unsigned u = (e & 0x80000000u) ? (e & 0x7FFFFFFFu) : ~e;
  return __uint_as_float(u);
}

__device__ __forceinline__ float int_gelu_f(float x){
  float t = x * INV_SQRT2;
  float at = fminf(fabsf(t), 1.769f);
  float u = at + GELU_B;                 // in [-1.769, 0]
  float p = GELU_A * (u * u) + 1.0f;
  float L = (t > 0.0f) ? p : ((t < 0.0f) ? -p : 0.0f);
  return x * 0.5f * (1.0f + L);
}

// blocks [0,1024): x min/max; [1024,1152): absmax w1 -> sc[3]; [1152,1280): absmax w2 -> sc[4]
__global__ __launch_bounds__(256) void reduce_stats(
    const float4* __restrict__ x, int nx4,
    const float4* __restrict__ w1, int n14,
    const float4* __restrict__ w2, int n24,
    unsigned* __restrict__ sc)
{
  __shared__ float ra[256], rb[256];
  const int tid = threadIdx.x;
  const int b = blockIdx.x;
  if (b < 1024){
    float lmin = 3.4e38f, lmax = -3.4e38f;
    for (long i = (long)b * 256 + tid; i < nx4; i += 1024L * 256L){
      float4 v = x[i];
      lmin = fminf(lmin, fminf(fminf(v.x, v.y), fminf(v.z, v.w)));
      lmax = fmaxf(lmax, fmaxf(fmaxf(v.x, v.y), fmaxf(v.z, v.w)));
    }
    ra[tid] = lmin; rb[tid] = lmax;
    __syncthreads();
    for (int s = 128; s > 0; s >>= 1){
      if (tid < s){ ra[tid] = fminf(ra[tid], ra[tid + s]); rb[tid] = fmaxf(rb[tid], rb[tid + s]); }
      __syncthreads();
    }
    if (tid == 0){
      atomicMin(&sc[0], enc_f(ra[0]));
      atomicMax(&sc[2], enc_f(rb[0]));
    }
  } else {
    const float4* w; int n4; int slot; int bl;
    if (b < 1152){ w = w1; n4 = n14; slot = 3; bl = b - 1024; }
    else         { w = w2; n4 = n24; slot = 4; bl = b - 1152; }
    float la = 0.0f;
    for (long i = (long)bl * 256 + tid; i < n4; i += 128L * 256L){
      float4 v = w[i];
      la = fmaxf(la, fmaxf(fmaxf(fabsf(v.x), fabsf(v.y)), fmaxf(fabsf(v.z), fabsf(v.w))));
    }
    ra[tid] = la;
    __syncthreads();
    for (int s = 128; s > 0; s >>= 1){
      if (tid < s) ra[tid] = fmaxf(ra[tid], ra[tid + s]);
      __syncthreads();
    }
    if (tid == 0) atomicMax(&sc[slot], __float_as_uint(ra[0]));
  }
}

// fused: blocks [0,2048) act-quant x -> qx ((q-128) int8, packed u32, LINEAR);
//        blocks [2048, 2048+H+D) weight-quant rows -> qw FRAGMENTED (+row sums)
// Fragment layout for weights: frag (rb,kb) = 1024B at ((rb*(K/32)+kb)<<10);
// byte lane*16+j = W[rb*32+(lane&31)][kb*32+(lane>>5)*16+j]  (proven in R3).
__global__ __launch_bounds__(256) void quant_all(
    const float4* __restrict__ x, unsigned* __restrict__ qx, long nx4,
    const float* __restrict__ w1, const float* __restrict__ w2,
    int8_t* __restrict__ qw1, int8_t* __restrict__ qw2,
    int* __restrict__ rs1, int* __restrict__ rs2,
    const unsigned* __restrict__ sc, int H, int D)
{
  const int tid = threadIdx.x;
  const int b = blockIdx.x;
  if (b < 2048){
    const float vmin = dec_f(sc[0]);
    const float vmax = dec_f(sc[2]);
    const float s  = fmaxf(vmax - vmin, 1e-8f) / 255.0f;
    const float zp = rintf(-vmin / s);
    for (long i = (long)b * 256 + tid; i < nx4; i += 2048L * 256L){
      float4 v = x[i];
      int q0 = (int)fminf(fmaxf(rintf(v.x / s) + zp, 0.0f), 255.0f) - 128;
      int q1 = (int)fminf(fmaxf(rintf(v.y / s) + zp, 0.0f), 255.0f) - 128;
      int q2 = (int)fminf(fmaxf(rintf(v.z / s) + zp, 0.0f), 255.0f) - 128;
      int q3 = (int)fminf(fmaxf(rintf(v.w / s) + zp, 0.0f), 255.0f) - 128;
      qx[i] = ((unsigned)(q0 & 255)) | ((unsigned)(q1 & 255) << 8) |
              ((unsigned)(q2 & 255) << 16) | ((unsigned)(q3 & 255) << 24);
    }
  } else {
    __shared__ int red[256];
    const int wb = b - 2048;
    const float* w; int8_t* q; int* rs; int K; int n; float s;
    if (wb < H){ w = w1; q = qw1; rs = rs1; K = D; n = wb;
                 s = fmaxf(__uint_as_float(sc[3]), 1e-8f) / 127.0f; }
    else       { w = w2; q = qw2; rs = rs2; K = H; n = wb - H;
                 s = fmaxf(__uint_as_float(sc[4]), 1e-8f) / 127.0f; }
    int sum = 0;
    const int c = tid;                       // chunk of 16 k (K/16 <= 192 < 256)
    if (c < (K >> 4)){
      const float4* wp = (const float4*)(w + (size_t)n * K + (size_t)c * 16);
      uint4 o; unsigned wds[4];
#pragma unroll
      for (int q4 = 0; q4 < 4; q4++){
        float4 v = wp[q4];
        int qa = (int)fminf(fmaxf(rintf(v.x / s), -128.0f), 127.0f);
        int qb = (int)fminf(fmaxf(rintf(v.y / s), -128.0f), 127.0f);
        int qc = (int)fminf(fmaxf(rintf(v.z / s), -128.0f), 127.0f);
        int qd = (int)fminf(fmaxf(rintf(v.w / s), -128.0f), 127.0f);
        sum += qa + qb + qc + qd;
        wds[q4] = ((unsigned)(qa & 255)) | ((unsigned)(qb & 255) << 8) |
                  ((unsigned)(qc & 255) << 16) | ((unsigned)(qd & 255) << 24);
      }
      o.x = wds[0]; o.y = wds[1]; o.z = wds[2]; o.w = wds[3];
      size_t off = ((((size_t)(n >> 5)) * (K >> 5) + (c >> 1)) << 10)
                 + ((size_t)(c & 1) << 9) + ((n & 31) << 4);
      *(uint4*)(q + off) = o;
    }
    red[tid] = sum;
    __syncthreads();
    for (int st = 128; st > 0; st >>= 1){
      if (tid < st) red[tid] += red[tid + st];
      __syncthreads();
    }
    if (tid == 0) rs[n] = red[0];
  }
}

// elementwise: fp16 g (LINEAR) -> int8 qg ((q-128), LINEAR), using g stats
__global__ __launch_bounds__(256) void quant_g(
    const vh8* __restrict__ g, uint2* __restrict__ qg, long n8,
    const unsigned* __restrict__ sc)
{
  const float gmin = dec_f(sc[1]), gmax = dec_f(sc[5]);
  const float qs  = fmaxf(gmax - gmin, 1e-8f) / 255.0f;
  const float qzp = rintf(-gmin / qs);
  const long stride = (long)gridDim.x * blockDim.x;
  for (long i = (long)blockIdx.x * blockDim.x + threadIdx.x; i < n8; i += stride){
    vh8 v = g[i];
    unsigned lo = 0, hi = 0;
#pragma unroll
    for (int j = 0; j < 4; j++){
      int q = (int)fminf(fmaxf(rintf((float)v[j] / qs) + qzp, 0.0f), 255.0f) - 128;
      lo |= ((unsigned)(q & 255)) << (8 * j);
    }
#pragma unroll
    for (int j = 0; j < 4; j++){
      int q = (int)fminf(fmaxf(rintf((float)v[4 + j] / qs) + qzp, 0.0f), 255.0f) - 128;
      hi |= ((unsigned)(q & 255)) << (8 * j);
    }
    uint2 o; o.x = lo; o.y = hi;
    qg[i] = o;
  }
}

// MODE 0: h->gelu-> g min/max atomics only (no store)          [fallback pass A]
// MODE 3: h->gelu-> store g fp16 + g min/max atomics            [main pass A]
// MODE 2: h->gelu-> quantize with g stats -> store int8 (q-128) [fallback pass B]
// MODE 1: h + bias -> store fp32 out                            [GEMM2]
//
// HYBRID GEMM (R0 skeleton, single change: B bypasses LDS).
// 128x128 tile, BK=64, 4 waves (2Mx2N) of 64x64, mfma_i32_32x32x32_i8.
// A: R0's 3-buffer LDS pipeline (gld_lds, chunk-XOR swizzle), 2 DMA/wave/tile.
// B: pre-FRAGMENTED (quant_all) -> direct global->VGPR dwordx4 loads from the
//    L2-resident 2.4MB weight panel, 1-deep ping-pong (4 loads/wave/K-step).
// vmcnt ledger (per wave, issue order inside iter = B(kt+1)x4 then A-dma(kt+2)x2):
//   top of iter kt outstanding = [A(kt)x2, B(kt)x4, A(kt+1)x2] -> vmcnt(2)
//   drains exactly A(kt)+B(kt), leaves A(kt+1) in flight. Never 0 in steady state.
// LDS 3x8KB=24KB; regs ~80 VGPR + 64 AGPR -> (256,3): 12 waves/CU.
template<int MODE>
__global__ __launch_bounds__(256, 3) void gemm_h(
    const int8_t* __restrict__ A, const int8_t* __restrict__ Bf,
    const int* __restrict__ rowsum, const float* __restrict__ bias,
    void* __restrict__ Cout, int M, int N, int K,
    unsigned* __restrict__ sc)
{
  __shared__ __align__(16) int8_t lds[3][8192];   // A tiles only

  const int tid  = threadIdx.x;
  const int lane = tid & 63;
  const int wave = tid >> 6;
  const int l31  = lane & 31;
  const int kh   = lane >> 5;          // 0/1 : which 16B half of a 32-k block
  const int n0   = blockIdx.x * 128;
  const int m0   = blockIdx.y * 128;
  const int wm   = (wave & 1) * 64;
  const int wn   = (wave >> 1) * 64;
  const int NT   = K >> 6;             // 64-wide K tiles (12 or 48, even)
  const int NKB  = K >> 5;             // 32-wide frag blocks for B

  // A staging (R0): wave w stages tile rows [32w,32w+32), 2 instrs of 16 rows.
  // lane L -> row rbase+(L>>2), LDS slot L&3, src chunk (L&3)^((row>>1)&3).
  int aoffs[2];
  const int ldstA[2] = { wave * 2048, wave * 2048 + 1024 };
#pragma unroll
  for (int t = 0; t < 2; t++){
    int rowl = wave * 32 + t * 16 + (lane >> 2);       // local tile row 0..127
    int csw  = ((lane & 3) ^ ((rowl >> 1) & 3)) << 4;  // swizzled source chunk
    int ga = m0 + rowl; if (ga >= M) ga = M - 1;       // clamp (dup rows, epilogue-guarded)
    aoffs[t] = ga * K + csw;
  }

  // A fragment read constants: slot s = (kk*2+kh) ^ ((l31>>1)&3)
  const int w2  = (l31 >> 1) & 3;
  const int sA0 = (kh ^ w2) << 4;
  int arow[2];
#pragma unroll
  for (int mi = 0; mi < 2; mi++) arow[mi] = (wm + mi * 32 + l31) * 64;

  // B fragment pointers (frag layout: cb-th 32-col block, frag idx 2*kt+kk)
  const int8_t* bpt[2];
#pragma unroll
  for (int nj = 0; nj < 2; nj++){
    int cb = (n0 + wn + nj * 32) >> 5;
    bpt[nj] = Bf + ((size_t)cb * NKB) * 1024 + lane * 16;
  }

  v16i acc[2][2] = {};
  v4i b0[2][2], b1[2][2];              // ping-pong B frags [kk][nj]

  // prologue (issue order matters for vmcnt ledger): A(0)x2, B(0)x4, A(1)x2
#pragma unroll
  for (int t = 0; t < 2; t++) GLD16(A + aoffs[t], &lds[0][ldstA[t]]);
#pragma unroll
  for (int kk = 0; kk < 2; kk++)
#pragma unroll
    for (int nj = 0; nj < 2; nj++)
      b0[kk][nj] = *(const v4i*)(bpt[nj] + (kk << 10));
#pragma unroll
  for (int t = 0; t < 2; t++) GLD16(A + aoffs[t] + 64, &lds[1][ldstA[t]]);

  int bcur = 0, bst = 2;

#define ITER(KT, BC, BN_) do{                                                  \
    if ((KT) + 1 < NT) __builtin_amdgcn_s_waitcnt(WAIT_VM2);                   \
    else               __builtin_amdgcn_s_waitcnt(WAIT_VM0);                   \
    __builtin_amdgcn_s_barrier();                                              \
    __builtin_amdgcn_sched_barrier(0);                                         \
    const int8_t* buf = &lds[bcur][0];                                         \
    v4i af[2][2];                                                              \
    _Pragma("unroll") for (int kk = 0; kk < 2; kk++)                           \
      _Pragma("unroll") for (int mi = 0; mi < 2; mi++)                         \
        af[kk][mi] = *(const v4i*)(buf + arow[mi] + (sA0 ^ (kk << 5)));        \
    if ((KT) + 1 < NT){                                                        \
      const int fb = 2 * ((KT) + 1);                                           \
      _Pragma("unroll") for (int kk = 0; kk < 2; kk++)                         \
        _Pragma("unroll") for (int nj = 0; nj < 2; nj++)                       \
          BN_[kk][nj] = *(const v4i*)(bpt[nj] + ((fb + kk) << 10));            \
    }                                                                          \
    if ((KT) + 2 < NT){                                                        \
      const int ko = ((KT) + 2) << 6;                                          \
      _Pragma("unroll") for (int t = 0; t < 2; t++)                            \
        GLD16(A + aoffs[t] + ko, &lds[bst][ldstA[t]]);                         \
    }                                                                          \
    __builtin_amdgcn_sched_barrier(0);                                         \
    _Pragma("unroll") for (int kk = 0; kk < 2; kk++)                           \
      _Pragma("unroll") for (int mi = 0; mi < 2; mi++)                         \
        _Pragma("unroll") for (int nj = 0; nj < 2; nj++)                       \
          acc[mi][nj] = __builtin_amdgcn_mfma_i32_32x32x32_i8(af[kk][mi], BC[kk][nj], acc[mi][nj], 0, 0, 0); \
    bcur = (bcur == 2) ? 0 : bcur + 1;                                         \
    bst  = (bst  == 2) ? 0 : bst  + 1;                                         \
  }while(0)

  for (int kt = 0; kt < NT; kt += 2){
    ITER(kt,     b0, b1);
    ITER(kt + 1, b1, b0);
  }
#undef ITER

  // epilogue scalars
  float s_h, off_h;
  if constexpr (MODE == 1){
    float gmin = dec_f(sc[1]), gmax = dec_f(sc[5]);
    float sg = fmaxf(gmax - gmin, 1e-8f) / 255.0f;
    float zp = rintf(-gmin / sg);
    float sw = fmaxf(__uint_as_float(sc[4]), 1e-8f) / 127.0f;
    s_h = sg * sw; off_h = 128.0f - zp;
  } else {
    float xmin = dec_f(sc[0]), xmax = dec_f(sc[2]);
    float sx = fmaxf(xmax - xmin, 1e-8f) / 255.0f;
    float zp = rintf(-xmin / sx);
    float sw = fmaxf(__uint_as_float(sc[3]), 1e-8f) / 127.0f;
    s_h = sx * sw; off_h = 128.0f - zp;
  }
  float qs = 1.0f, qzp = 0.0f;
  if constexpr (MODE == 2){
    float gmin = dec_f(sc[1]), gmax = dec_f(sc[5]);
    qs = fmaxf(gmax - gmin, 1e-8f) / 255.0f;
    qzp = rintf(-gmin / qs);
  }

  // C/D 32x32 layout: col = lane&31, row = (reg&3) + 8*(reg>>2) + 4*(lane>>5)
  float lmin = 3.4e38f, lmax = -3.4e38f;
#pragma unroll
  for (int nj = 0; nj < 2; nj++){
    const int n = n0 + wn + nj * 32 + l31;
    const float rsv = off_h * (float)rowsum[n];
    const float bv = bias[n];
#pragma unroll
    for (int mi = 0; mi < 2; mi++){
      const int mbase = m0 + wm + mi * 32 + 4 * kh;
#pragma unroll
      for (int r = 0; r < 16; r++){
        const int m = mbase + (r & 3) + 8 * (r >> 2);
        if (m < M){
          float h = s_h * ((float)acc[mi][nj][r] + rsv) + bv;
          if constexpr (MODE == 0){
            float gv = int_gelu_f(h);
            lmin = fminf(lmin, gv); lmax = fmaxf(lmax, gv);
          } else if constexpr (MODE == 3){
            float gv = int_gelu_f(h);
            lmin = fminf(lmin, gv); lmax = fmaxf(lmax, gv);
            ((_Float16*)Cout)[(size_t)m * N + n] = (_Float16)gv;
          } else if constexpr (MODE == 2){
            float gv = int_gelu_f(h);
            float qf = fminf(fmaxf(rintf(gv / qs) + qzp, 0.0f), 255.0f);
            ((int8_t*)Cout)[(size_t)m * N + n] = (int8_t)((int)qf - 128);
          } else {
            ((float*)Cout)[(size_t)m * N + n] = h;
          }
        }
      }
    }
  }

  if constexpr (MODE == 0 || MODE == 3){
    __syncthreads();                   // all waves done with LDS -> reuse as scratch
    float* redA = (float*)&lds[0][0];
    float* redB = ((float*)&lds[0][0]) + 256;
    redA[tid] = lmin; redB[tid] = lmax;
    __syncthreads();
    for (int st = 128; st > 0; st >>= 1){
      if (tid < st){
        redA[tid] = fminf(redA[tid], redA[tid + st]);
        redB[tid] = fmaxf(redB[tid], redB[tid + st]);
      }
      __syncthreads();
    }
    if (tid == 0){
      atomicMin(&sc[1], enc_f(redA[0]));
      atomicMax(&sc[5], enc_f(redB[0]));
    }
  }
}

extern "C" void kernel_launch(void* const* d_in, const int* in_sizes, int n_in,
                              void* d_out, int out_size, void* d_ws, size_t ws_size,
                              hipStream_t stream)
{
  const float* x  = (const float*)d_in[0];
  const float* w1 = (const float*)d_in[1];
  const float* b1 = (const float*)d_in[2];
  const float* w2 = (const float*)d_in[3];
  const float* b2 = (const float*)d_in[4];
  float* out = (float*)d_out;

  const int H = in_sizes[2];            // 3072
  const int D = in_sizes[4];            // 768
  const int M = in_sizes[0] / D;        // 12608

  char* ws = (char*)d_ws;
  unsigned* sc = (unsigned*)ws;
  size_t off = 256;
  int8_t* qx  = (int8_t*)(ws + off); off += (size_t)M * D;   // 9.68 MB  (linear)
  int8_t* qw1 = (int8_t*)(ws + off); off += (size_t)H * D;   // 2.36 MB  (fragmented)
  int8_t* qw2 = (int8_t*)(ws + off); off += (size_t)D * H;   // 2.36 MB  (fragmented)
  int* rs1 = (int*)(ws + off); off += (size_t)H * 4;
  int* rs2 = (int*)(ws + off); off += 4096;
  int8_t* qg  = (int8_t*)(ws + off); off += (size_t)M * H;   // 38.7 MB  (linear)
  _Float16* g16 = (_Float16*)(ws + off);                      // 77.5 MB  (linear)
  const size_t need_big = off + (size_t)M * H * 2;
  (void)n_in; (void)out_size;

  // scalar init: slots 0,1 = 0xFFFFFFFF (encoded +inf for min); 2..5 = 0
  hipMemsetAsync(sc, 0xFF, 8, stream);
  hipMemsetAsync(sc + 2, 0x00, 16, stream);

  reduce_stats<<<dim3(1280), dim3(256), 0, stream>>>(
      (const float4*)x, M * D / 4,
      (const float4*)w1, H * D / 4,
      (const float4*)w2, D * H / 4, sc);

  quant_all<<<dim3(2048 + H + D), dim3(256), 0, stream>>>(
      (const float4*)x, (unsigned*)qx, (long)M * D / 4,
      w1, w2, qw1, qw2, rs1, rs2, sc, H, D);

  const dim3 g1(H / 128, (M + 127) / 128), g2(D / 128, (M + 127) / 128), blk(256);

  if (ws_size >= need_big){
    // GEMM1 (single pass): g stats + store g fp16
    gemm_h<3><<<g1, blk, 0, stream>>>(qx, qw1, rs1, b1, g16, M, H, D, sc);
    // elementwise quantize g -> qg
    quant_g<<<dim3(2048), dim3(256), 0, stream>>>(
        (const vh8*)g16, (uint2*)qg, (long)M * H / 8, sc);
  } else {
    // fallback: exact 2-pass GEMM1 (stats, then quantize)
    gemm_h<0><<<g1, blk, 0, stream>>>(qx, qw1, rs1, b1, nullptr, M, H, D, sc);
    gemm_h<2><<<g1, blk, 0, stream>>>(qx, qw1, rs1, b1, qg, M, H, D, sc);
  }

  // GEMM2: out = qg @ qw2^T + b2
  gemm_h<1><<<g2, blk, 0, stream>>>(qg, qw2, rs2, b2, out, M, D, H, sc);
}

// Round 8
// 307.090 us; speedup vs baseline: 1.0977x; 1.0825x over previous
//
#include <hip/hip_runtime.h>
#include <stdint.h>
#include <stddef.h>

typedef int v4i  __attribute__((ext_vector_type(4)));
typedef int v16i __attribute__((ext_vector_type(16)));
typedef _Float16 vh8 __attribute__((ext_vector_type(8)));

#define GELU_A   (-0.2888f)
#define GELU_B   (-1.769f)
#define INV_SQRT2 0.70710678118654752440f

// async 16B global->LDS (lane i's 16B lands at ldsbase + i*16; ldsbase wave-uniform)
#define GLD16(gp, lp) __builtin_amdgcn_global_load_lds( \
    (const __attribute__((address_space(1))) unsigned int*)(gp), \
    (__attribute__((address_space(3))) unsigned int*)(lp), 16, 0, 0)

// gfx9 s_waitcnt immediates: vmcnt[3:0]=bits3:0, expcnt=bits6:4, lgkmcnt=bits11:8
#define WAIT_VM4 0x0F74   // vmcnt(4)
#define WAIT_VM0 0x0F70   // vmcnt(0)

// scalar slots: sc[0]=enc(xmin) sc[1]=enc(gmin)  [init 0xFFFFFFFF]
//               sc[2]=enc(xmax) sc[3]=|w1|max bits sc[4]=|w2|max bits sc[5]=enc(gmax) [init 0]

__device__ __forceinline__ unsigned enc_f(float f){
  unsigned u = __float_as_uint(f);
  return (u & 0x80000000u) ? ~u : (u | 0x80000000u);
}
__device__ __forceinline__ float dec_f(unsigned e){
  unsigned u = (e & 0x80000000u) ? (e & 0x7FFFFFFFu) : ~e;
  return __uint_as_float(u);
}

__device__ __forceinline__ float int_gelu_f(float x){
  float t = x * INV_SQRT2;
  float at = fminf(fabsf(t), 1.769f);
  float u = at + GELU_B;                 // in [-1.769, 0]
  float p = GELU_A * (u * u) + 1.0f;
  float L = (t > 0.0f) ? p : ((t < 0.0f) ? -p : 0.0f);
  return x * 0.5f * (1.0f + L);
}

// blocks [0,1024): x min/max; [1024,1152): absmax w1 -> sc[3]; [1152,1280): absmax w2 -> sc[4]
__global__ __launch_bounds__(256) void reduce_stats(
    const float4* __restrict__ x, int nx4,
    const float4* __restrict__ w1, int n14,
    const float4* __restrict__ w2, int n24,
    unsigned* __restrict__ sc)
{
  __shared__ float ra[256], rb[256];
  const int tid = threadIdx.x;
  const int b = blockIdx.x;
  if (b < 1024){
    float lmin = 3.4e38f, lmax = -3.4e38f;
    for (long i = (long)b * 256 + tid; i < nx4; i += 1024L * 256L){
      float4 v = x[i];
      lmin = fminf(lmin, fminf(fminf(v.x, v.y), fminf(v.z, v.w)));
      lmax = fmaxf(lmax, fmaxf(fmaxf(v.x, v.y), fmaxf(v.z, v.w)));
    }
    ra[tid] = lmin; rb[tid] = lmax;
    __syncthreads();
    for (int s = 128; s > 0; s >>= 1){
      if (tid < s){ ra[tid] = fminf(ra[tid], ra[tid + s]); rb[tid] = fmaxf(rb[tid], rb[tid + s]); }
      __syncthreads();
    }
    if (tid == 0){
      atomicMin(&sc[0], enc_f(ra[0]));
      atomicMax(&sc[2], enc_f(rb[0]));
    }
  } else {
    const float4* w; int n4; int slot; int bl;
    if (b < 1152){ w = w1; n4 = n14; slot = 3; bl = b - 1024; }
    else         { w = w2; n4 = n24; slot = 4; bl = b - 1152; }
    float la = 0.0f;
    for (long i = (long)bl * 256 + tid; i < n4; i += 128L * 256L){
      float4 v = w[i];
      la = fmaxf(la, fmaxf(fmaxf(fabsf(v.x), fabsf(v.y)), fmaxf(fabsf(v.z), fabsf(v.w))));
    }
    ra[tid] = la;
    __syncthreads();
    for (int s = 128; s > 0; s >>= 1){
      if (tid < s) ra[tid] = fmaxf(ra[tid], ra[tid + s]);
      __syncthreads();
    }
    if (tid == 0) atomicMax(&sc[slot], __float_as_uint(ra[0]));
  }
}

// fused: blocks [0,2048) act-quant x -> qx ((q-128) int8, packed u32);
//        blocks [2048, 2048+H+D) weight-quant rows (+row sums)
__global__ __launch_bounds__(256) void quant_all(
    const float4* __restrict__ x, unsigned* __restrict__ qx, long nx4,
    const float* __restrict__ w1, const float* __restrict__ w2,
    int8_t* __restrict__ qw1, int8_t* __restrict__ qw2,
    int* __restrict__ rs1, int* __restrict__ rs2,
    const unsigned* __restrict__ sc, int H, int D)
{
  const int tid = threadIdx.x;
  const int b = blockIdx.x;
  if (b < 2048){
    const float vmin = dec_f(sc[0]);
    const float vmax = dec_f(sc[2]);
    const float s  = fmaxf(vmax - vmin, 1e-8f) / 255.0f;
    const float zp = rintf(-vmin / s);
    for (long i = (long)b * 256 + tid; i < nx4; i += 2048L * 256L){
      float4 v = x[i];
      int q0 = (int)fminf(fmaxf(rintf(v.x / s) + zp, 0.0f), 255.0f) - 128;
      int q1 = (int)fminf(fmaxf(rintf(v.y / s) + zp, 0.0f), 255.0f) - 128;
      int q2 = (int)fminf(fmaxf(rintf(v.z / s) + zp, 0.0f), 255.0f) - 128;
      int q3 = (int)fminf(fmaxf(rintf(v.w / s) + zp, 0.0f), 255.0f) - 128;
      qx[i] = ((unsigned)(q0 & 255)) | ((unsigned)(q1 & 255) << 8) |
              ((unsigned)(q2 & 255) << 16) | ((unsigned)(q3 & 255) << 24);
    }
  } else {
    __shared__ int red[256];
    const int wb = b - 2048;
    const float* w; int8_t* q; int* rs; int K; int n; float s;
    if (wb < H){ w = w1; q = qw1; rs = rs1; K = D; n = wb;
                 s = fmaxf(__uint_as_float(sc[3]), 1e-8f) / 127.0f; }
    else       { w = w2; q = qw2; rs = rs2; K = H; n = wb - H;
                 s = fmaxf(__uint_as_float(sc[4]), 1e-8f) / 127.0f; }
    int sum = 0;
    for (int k = tid; k < K; k += 256){
      float v = w[(size_t)n * K + k];
      float qf = fminf(fmaxf(rintf(v / s), -128.0f), 127.0f);
      int qi = (int)qf;
      q[(size_t)n * K + k] = (int8_t)qi;
      sum += qi;
    }
    red[tid] = sum;
    __syncthreads();
    for (int st = 128; st > 0; st >>= 1){
      if (tid < st) red[tid] += red[tid + st];
      __syncthreads();
    }
    if (tid == 0) rs[n] = red[0];
  }
}

// elementwise: fp16 g -> int8 qg ((q-128)), using g stats
__global__ __launch_bounds__(256) void quant_g(
    const vh8* __restrict__ g, uint2* __restrict__ qg, long n8,
    const unsigned* __restrict__ sc)
{
  const float gmin = dec_f(sc[1]), gmax = dec_f(sc[5]);
  const float qs  = fmaxf(gmax - gmin, 1e-8f) / 255.0f;
  const float qzp = rintf(-gmin / qs);
  const long stride = (long)gridDim.x * blockDim.x;
  for (long i = (long)blockIdx.x * blockDim.x + threadIdx.x; i < n8; i += stride){
    vh8 v = g[i];
    unsigned lo = 0, hi = 0;
#pragma unroll
    for (int j = 0; j < 4; j++){
      int q = (int)fminf(fmaxf(rintf((float)v[j] / qs) + qzp, 0.0f), 255.0f) - 128;
      lo |= ((unsigned)(q & 255)) << (8 * j);
    }
#pragma unroll
    for (int j = 0; j < 4; j++){
      int q = (int)fminf(fmaxf(rintf((float)v[4 + j] / qs) + qzp, 0.0f), 255.0f) - 128;
      hi |= ((unsigned)(q & 255)) << (8 * j);
    }
    uint2 o; o.x = lo; o.y = hi;
    qg[i] = o;
  }
}

// MODE 0: h->gelu-> g min/max atomics only (no store)          [fallback pass A]
// MODE 3: h->gelu-> store g fp16 (LDS-transposed, coalesced) + g min/max [main pass A]
// MODE 2: h->gelu-> quantize with g stats -> store int8 (q-128) [fallback pass B]
// MODE 1: h + bias -> store fp32 out                            [GEMM2]
//
// R0 structure restored verbatim: 128x128 tile, BK=64, mfma_i32_32x32x32_i8,
// 4 waves each 64x64 (2x2 of 32x32), 3-stage pipeline, 3 LDS buffers
// (48KB -> 3 blocks/CU), vmcnt(4) steady state.
// R8 change (MODE 3 only): epilogue writes the wave's 64x64 fp16 tile into a
// private padded LDS buffer (row stride 72 fp16 = 144B, 16B-aligned), then
// copies out 8x {ds_read_b128 + global_store_dwordx4} = fully-coalesced
// full-line stores, replacing 128 scalar 2B stores (64B segments) that caused
// write-allocate FETCH (+~30MB) and WRITE (+~28MB) amplification on g16.
template<int MODE>
__global__ __launch_bounds__(256) void gemm_i8(
    const int8_t* __restrict__ A, const int8_t* __restrict__ Bm,
    const int* __restrict__ rowsum, const float* __restrict__ bias,
    void* __restrict__ Cout, int M, int N, int K,
    unsigned* __restrict__ sc)
{
  __shared__ __align__(16) int8_t lds[3][16384];   // per buf: A @0, B @8192

  const int tid  = threadIdx.x;
  const int lane = tid & 63;
  const int wave = tid >> 6;
  const int l31  = lane & 31;
  const int kh   = lane >> 5;          // 0/1 : which 16B half of a 32-k block
  const int n0   = blockIdx.x * 128;
  const int m0   = blockIdx.y * 128;
  const int wm   = (wave & 1) * 64;
  const int wn   = (wave >> 1) * 64;

  // staging: wave w stages tile rows [32w,32w+32), 2 instrs of 16 rows each per
  // operand. lane L -> row rbase+(L>>2), LDS slot L&3, src chunk (L&3)^((row>>1)&3).
  int aoffs[2], boffs[2];
  const int ldst[2] = { wave * 2048, wave * 2048 + 1024 };
#pragma unroll
  for (int t = 0; t < 2; t++){
    int rowl = wave * 32 + t * 16 + (lane >> 2);       // local tile row 0..127
    int csw  = ((lane & 3) ^ ((rowl >> 1) & 3)) << 4;  // swizzled source chunk
    int ga = m0 + rowl; if (ga >= M) ga = M - 1;
    aoffs[t] = ga * K + csw;
    boffs[t] = (n0 + rowl) * K + csw;
  }

  // fragment read constants: slot s = (kk*2+kh) ^ ((l31>>1)&3)
  const int w2  = (l31 >> 1) & 3;
  const int sA0 = (kh ^ w2) << 4;
  int arow[2], brow[2];
#pragma unroll
  for (int mi = 0; mi < 2; mi++){
    arow[mi] = (wm + mi * 32 + l31) * 64;
    brow[mi] = (wn + mi * 32 + l31) * 64;
  }

  v16i acc[2][2] = {};
  const int NT = K >> 6;

  // prologue: stage tiles 0,1 into bufs 0,1 (issue order = vmcnt order)
#pragma unroll
  for (int t = 0; t < 2; t++){
    GLD16(A  + aoffs[t],      &lds[0][ldst[t]]);
    GLD16(Bm + boffs[t],      &lds[0][8192 + ldst[t]]);
  }
#pragma unroll
  for (int t = 0; t < 2; t++){
    GLD16(A  + aoffs[t] + 64, &lds[1][ldst[t]]);
    GLD16(Bm + boffs[t] + 64, &lds[1][8192 + ldst[t]]);
  }

  for (int kt = 0; kt < NT; kt++){
    const int8_t* buf = lds[kt % 3];
    if (kt + 1 < NT) __builtin_amdgcn_s_waitcnt(WAIT_VM4);
    else             __builtin_amdgcn_s_waitcnt(WAIT_VM0);
    __builtin_amdgcn_s_barrier();          // raw: no compiler vmcnt(0) fence
    __builtin_amdgcn_sched_barrier(0);     // nothing (esp. next DMA) crosses up

    v4i af[2][2], bf[2][2];                // [kk][mi]
#pragma unroll
    for (int kk = 0; kk < 2; kk++){
      const int sb = sA0 ^ (kk << 5);
#pragma unroll
      for (int mi = 0; mi < 2; mi++){
        af[kk][mi] = *(const v4i*)(buf + arow[mi] + sb);
        bf[kk][mi] = *(const v4i*)(buf + 8192 + brow[mi] + sb);
      }
    }

    if (kt + 2 < NT){                      // prefetch distance 2
      int8_t* nbuf = lds[(kt + 2) % 3];
      const int ko = (kt + 2) << 6;
#pragma unroll
      for (int t = 0; t < 2; t++){
        GLD16(A  + aoffs[t] + ko, nbuf + ldst[t]);
        GLD16(Bm + boffs[t] + ko, nbuf + 8192 + ldst[t]);
      }
    }

#pragma unroll
    for (int kk = 0; kk < 2; kk++)
#pragma unroll
      for (int mi = 0; mi < 2; mi++)
#pragma unroll
        for (int nj = 0; nj < 2; nj++)
          acc[mi][nj] = __builtin_amdgcn_mfma_i32_32x32x32_i8(af[kk][mi], bf[kk][nj], acc[mi][nj], 0, 0, 0);
  }

  // epilogue scalars
  float s_h, off_h;
  if constexpr (MODE == 1){
    float gmin = dec_f(sc[1]), gmax = dec_f(sc[5]);
    float sg = fmaxf(gmax - gmin, 1e-8f) / 255.0f;
    float zp = rintf(-gmin / sg);
    float sw = fmaxf(__uint_as_float(sc[4]), 1e-8f) / 127.0f;
    s_h = sg * sw; off_h = 128.0f - zp;
  } else {
    float xmin = dec_f(sc[0]), xmax = dec_f(sc[2]);
    float sx = fmaxf(xmax - xmin, 1e-8f) / 255.0f;
    float zp = rintf(-xmin / sx);
    float sw = fmaxf(__uint_as_float(sc[3]), 1e-8f) / 127.0f;
    s_h = sx * sw; off_h = 128.0f - zp;
  }
  float qs = 1.0f, qzp = 0.0f;
  if constexpr (MODE == 2){
    float gmin = dec_f(sc[1]), gmax = dec_f(sc[5]);
    qs = fmaxf(gmax - gmin, 1e-8f) / 255.0f;
    qzp = rintf(-gmin / qs);
  }

  // MODE 3: per-wave private LDS transpose buffer (64 rows x 72 fp16 = 9216B)
  _Float16* tb = nullptr;
  if constexpr (MODE == 3){
    __syncthreads();                   // K-loop LDS traffic fully complete
    tb = (_Float16*)(&lds[0][0]) + (size_t)wave * 4608;
  }

  // C/D 32x32 layout: col = lane&31, row = (reg&3) + 8*(reg>>2) + 4*(lane>>5)
  float lmin = 3.4e38f, lmax = -3.4e38f;
#pragma unroll
  for (int nj = 0; nj < 2; nj++){
    const int n = n0 + wn + nj * 32 + l31;
    const float rsv = off_h * (float)rowsum[n];
    const float bv = bias[n];
#pragma unroll
    for (int mi = 0; mi < 2; mi++){
      const int mbase = m0 + wm + mi * 32 + 4 * kh;
#pragma unroll
      for (int r = 0; r < 16; r++){
        const int m = mbase + (r & 3) + 8 * (r >> 2);
        float h = s_h * ((float)acc[mi][nj][r] + rsv) + bv;
        if constexpr (MODE == 3){
          float gv = int_gelu_f(h);
          if (m < M){ lmin = fminf(lmin, gv); lmax = fmaxf(lmax, gv); }
          const int lmr = mi * 32 + 4 * kh + (r & 3) + 8 * (r >> 2);
          const int lnr = nj * 32 + l31;
          tb[lmr * 72 + lnr] = (_Float16)gv;
        } else if (m < M){
          if constexpr (MODE == 0){
            float gv = int_gelu_f(h);
            lmin = fminf(lmin, gv); lmax = fmaxf(lmax, gv);
          } else if constexpr (MODE == 2){
            float gv = int_gelu_f(h);
            float qf = fminf(fmaxf(rintf(gv / qs) + qzp, 0.0f), 255.0f);
            ((int8_t*)Cout)[(size_t)m * N + n] = (int8_t)((int)qf - 128);
          } else {
            ((float*)Cout)[(size_t)m * N + n] = h;
          }
        }
      }
    }
  }

  if constexpr (MODE == 3){
    __syncthreads();                   // drains lgkm; tb regions are per-wave private
#pragma unroll
    for (int it = 0; it < 8; it++){
      const int lr = it * 8 + (lane >> 3);         // local row 0..63
      const int c8 = (lane & 7) * 8;               // fp16 col start (16B chunks)
      vh8 v = *(const vh8*)(tb + lr * 72 + c8);    // 16B aligned (144B row stride)
      const int gm = m0 + wm + lr;
      if (gm < M)
        *(vh8*)((_Float16*)Cout + (size_t)gm * N + (n0 + wn + c8)) = v;
    }
  }

  if constexpr (MODE == 0 || MODE == 3){
    __syncthreads();                   // all waves done with LDS -> reuse as scratch
    float* redA = (float*)&lds[0][0];
    float* redB = ((float*)&lds[0][0]) + 256;
    redA[tid] = lmin; redB[tid] = lmax;
    __syncthreads();
    for (int st = 128; st > 0; st >>= 1){
      if (tid < st){
        redA[tid] = fminf(redA[tid], redA[tid + st]);
        redB[tid] = fmaxf(redB[tid], redB[tid + st]);
      }
      __syncthreads();
    }
    if (tid == 0){
      atomicMin(&sc[1], enc_f(redA[0]));
      atomicMax(&sc[5], enc_f(redB[0]));
    }
  }
}

extern "C" void kernel_launch(void* const* d_in, const int* in_sizes, int n_in,
                              void* d_out, int out_size, void* d_ws, size_t ws_size,
                              hipStream_t stream)
{
  const float* x  = (const float*)d_in[0];
  const float* w1 = (const float*)d_in[1];
  const float* b1 = (const float*)d_in[2];
  const float* w2 = (const float*)d_in[3];
  const float* b2 = (const float*)d_in[4];
  float* out = (float*)d_out;

  const int H = in_sizes[2];            // 3072
  const int D = in_sizes[4];            // 768
  const int M = in_sizes[0] / D;        // 12608

  char* ws = (char*)d_ws;
  unsigned* sc = (unsigned*)ws;
  size_t off = 256;
  int8_t* qx  = (int8_t*)(ws + off); off += (size_t)M * D;   // 9.68 MB
  int8_t* qw1 = (int8_t*)(ws + off); off += (size_t)H * D;   // 2.36 MB
  int8_t* qw2 = (int8_t*)(ws + off); off += (size_t)D * H;   // 2.36 MB
  int* rs1 = (int*)(ws + off); off += (size_t)H * 4;
  int* rs2 = (int*)(ws + off); off += 4096;
  int8_t* qg  = (int8_t*)(ws + off); off += (size_t)M * H;   // 38.7 MB
  _Float16* g16 = (_Float16*)(ws + off);                      // 77.5 MB (big path)
  const size_t need_big = off + (size_t)M * H * 2;
  (void)n_in; (void)out_size;

  // scalar init: slots 0,1 = 0xFFFFFFFF (encoded +inf for min); 2..5 = 0
  hipMemsetAsync(sc, 0xFF, 8, stream);
  hipMemsetAsync(sc + 2, 0x00, 16, stream);

  reduce_stats<<<dim3(1280), dim3(256), 0, stream>>>(
      (const float4*)x, M * D / 4,
      (const float4*)w1, H * D / 4,
      (const float4*)w2, D * H / 4, sc);

  quant_all<<<dim3(2048 + H + D), dim3(256), 0, stream>>>(
      (const float4*)x, (unsigned*)qx, (long)M * D / 4,
      w1, w2, qw1, qw2, rs1, rs2, sc, H, D);

  const dim3 g1(H / 128, (M + 127) / 128), g2(D / 128, (M + 127) / 128), blk(256);

  if (ws_size >= need_big){
    // GEMM1 (single pass): g stats + store g fp16 (coalesced via LDS transpose)
    gemm_i8<3><<<g1, blk, 0, stream>>>(qx, qw1, rs1, b1, g16, M, H, D, sc);
    // elementwise quantize g -> qg
    quant_g<<<dim3(2048), blk, 0, stream>>>(
        (const vh8*)g16, (uint2*)qg, (long)M * H / 8, sc);
  } else {
    // fallback: exact 2-pass GEMM1 (stats, then quantize)
    gemm_i8<0><<<g1, blk, 0, stream>>>(qx, qw1, rs1, b1, nullptr, M, H, D, sc);
    gemm_i8<2><<<g1, blk, 0, stream>>>(qx, qw1, rs1, b1, qg, M, H, D, sc);
  }

  // GEMM2: out = qg @ qw2^T + b2
  gemm_i8<1><<<g2, blk, 0, stream>>>(qg, qw2, rs2, b2, out, M, D, H, sc);
}